// Round 14
// baseline (192.662 us; speedup 1.0000x reference)
//
#include <hip/hip_runtime.h>
#include <math.h>

// MMD loss, fp16 MFMA. N=M=4096, D=1024, sigma^2=2025.
// Round 24: MFMA-BOUND GEOMETRY + COUNTED VMCNT (the untested matrix cell).
// R13 reproduced the stable baseline (mmd 83us = 847 TF, the 128^2-class
// ceiling). Session matrix: thin wave-tiles (64x64) are LDS-bound (ratio
// 1.5) -> schedules can't help (R1/R2/R3/R5); fat tiles with 4 waves ->
// register collapse (R8). THIS round: per-wave 128x64 (MFMA 1242cy/step >
// LDS ~1100cy/step -- first MFMA-bound ratio), 8-wave 256^2 block (2
// waves/SIMD guaranteed at <=256 regs), ring-3 LDS (96KB, 1 blk/CU),
// counted vmcnt(4) -- NEVER drained to 0 in the loop (T4, the documented
// +38-73% lever), one barrier per K-step. Race proofs: stage of tile t+2
// targets slot (t-1)%3 whose readers retired before the t-1 barrier that
// all waves passed; vmcnt(4) at step end leaves only this step's 4 stages
// outstanding -> tile t+1 landed before its reads. Dummy clamped stages
// keep vmcnt counting uniform through the tail. Grid: 528 blocks
// (2x136 triangular 256^2 + 16x16 XY). Regs: 128 acc + 48 frag + ~40
// addr ~= 215 <= 256 cap (512,2). Convert + packing + 0-conflict swizzle
// + fp64 partials unchanged from R13.
// FALSIFIER: mmd >= 83us or spill (WRITE_SIZE >> 1MB) -> revert R13,
// declare floor.

typedef _Float16 f16_t;
typedef _Float16 f16x4 __attribute__((ext_vector_type(4)));
typedef _Float16 f16x8 __attribute__((ext_vector_type(8)));
typedef float floatx4 __attribute__((ext_vector_type(4)));

#define NROWS 4096
#define MROWS 4096
#define DDIM  1024
#define BK    32                      // fp16 elements per K-step (64 B/row)
#define NKT   (DDIM / BK)             // 32 K-steps
#define PSTRIDE (4096 * BK)           // f16 elems per packed K-panel (256 KB)
#define BM2   256                     // block tile (square)
#define NT2   (NROWS / BM2)           // 16 tiles per dim
#define TRI2  (NT2 * (NT2 + 1) / 2)   // 136 triangular tiles
#define NBLK  (2 * TRI2 + NT2 * NT2)  // 528 blocks
#define TSLOT (BM2 * BK)              // 8192 f16 = 16 KB per tile-slot

// ---------------------------------------------------------------- convert
// Wave-per-row: 2048 blocks x 4 waves cover 8192 rows. Each lane loads
// 4 float4 (fully coalesced), converts to fp16, stores to the PACKED layout
// Xp[kt][row][32]: lane l, iter c covers k = c*256+l*4 -> panel c*8+(l>>3),
// pos (l&7)*4. Norm of the ROUNDED row shuffle-reduced in-wave.
__global__ __launch_bounds__(256) void convert_kernel(
    const float* __restrict__ X, const float* __restrict__ Y,
    f16_t* __restrict__ Xp, f16_t* __restrict__ Yp,
    float* __restrict__ nx, float* __restrict__ ny) {
    const int wid  = threadIdx.x >> 6;
    const int lane = threadIdx.x & 63;
    const int row  = blockIdx.x * 4 + wid;        // 0..8191
    const float* src;
    f16_t* dstp;
    float* nrm;
    int r;
    if (row < NROWS) {
        r = row;         src = X + (size_t)r * DDIM;
        dstp = Xp;  nrm = nx;
    } else {
        r = row - NROWS; src = Y + (size_t)r * DDIM;
        dstp = Yp;  nrm = ny;
    }
    const float4* s4 = (const float4*)src;        // 256 float4 per row
    float s = 0.f;
    #pragma unroll
    for (int c = 0; c < 4; c++) {
        float4 v = s4[c * 64 + lane];
        f16x4 h;
        h[0] = (f16_t)v.x; h[1] = (f16_t)v.y;
        h[2] = (f16_t)v.z; h[3] = (f16_t)v.w;
        // k = c*256 + lane*4 -> kt = c*8 + (lane>>3), pos = (lane&7)*4
        *(f16x4*)(dstp + (size_t)(c * 8 + (lane >> 3)) * PSTRIDE
                       + (size_t)r * BK + (lane & 7) * 4) = h;
        float h0 = (float)h[0], h1 = (float)h[1];
        float h2 = (float)h[2], h3 = (float)h[3];
        s += h0 * h0 + h1 * h1 + h2 * h2 + h3 * h3;
    }
    #pragma unroll
    for (int off = 32; off > 0; off >>= 1) s += __shfl_down(s, off);
    if (lane == 0) nrm[r] = s;
}

// ---------------------------------------------------------------- main GEMM
// Stage tile tile_ into ring slot slot_: per wave 2 A-glds + 2 B-glds,
// each 1KB contiguous in the packed panel (16 rows x 64B).
#define STAGE4(tile_, slot_) do {                                              \
    const size_t ko_ = (size_t)(tile_) * PSTRIDE;                              \
    _Pragma("unroll")                                                          \
    for (int i_ = 0; i_ < 2; i_++) {                                           \
        __builtin_amdgcn_global_load_lds(                                      \
            (const __attribute__((address_space(1))) void*)(gA[i_] + ko_),     \
            (__attribute__((address_space(3))) void*)(&ldsA[slot_][offAB[i_]]),\
            16, 0, 0);                                                         \
        __builtin_amdgcn_global_load_lds(                                      \
            (const __attribute__((address_space(1))) void*)(gB[i_] + ko_),     \
            (__attribute__((address_space(3))) void*)(&ldsB[slot_][offAB[i_]]),\
            16, 0, 0);                                                         \
    }                                                                          \
  } while (0)

__global__ __launch_bounds__(512, 2) void mmd_mfma(
    const f16_t* __restrict__ Xp, const f16_t* __restrict__ Yp,
    const float* __restrict__ nx, const float* __restrict__ ny,
    double* __restrict__ partials) {
    // Ring-3: 3 x (A 256x32 + B 256x32) fp16 = 96 KB. Row r of a tile
    // stores logical chunk c (16B) at phys chunk c ^ ((r>>1)&3) -- the
    // measured-0-conflict pattern (R7/R13).
    __shared__ __align__(16) f16_t ldsA[3][TSLOT];
    __shared__ __align__(16) f16_t ldsB[3][TSLOT];
    __shared__ double wred[8];

    const int b = blockIdx.x;
    const f16_t *Ap, *Bp;             // packed panel bases (panel 0)
    const float *nA, *nB;
    int tr, tc;
    double coef;
    if (b < 2 * TRI2) {
        int u = (b < TRI2) ? b : b - TRI2;
        int r = 0;
        while (u >= NT2 - r) { u -= NT2 - r; r++; }
        tr = r; tc = r + u;
        double w = (tr == tc) ? 1.0 : 2.0;   // off-diagonal tiles count twice
        if (b < TRI2) { Ap = Xp; Bp = Xp; nA = nx; nB = nx;
                        coef = w / ((double)NROWS * (double)(NROWS - 1)); }
        else          { Ap = Yp; Bp = Yp; nA = ny; nB = ny;
                        coef = w / ((double)MROWS * (double)(MROWS - 1)); }
    } else {
        int u = b - 2 * TRI2;
        tr = u >> 4; tc = u & 15;
        Ap = Xp; Bp = Yp; nA = nx; nB = ny;
        coef = -2.0 / ((double)NROWS * (double)MROWS);
    }
    const int arow0 = tr * BM2, brow0 = tc * BM2;

    const int tid  = threadIdx.x;
    const int wave = tid >> 6;          // 0..7; 2(M) x 4(N)
    const int lane = tid & 63;
    const int wm   = wave >> 2;         // 0..1 : 128 A-rows each
    const int wn   = wave & 3;          // 0..3 : 64 B-rows each
    const int m    = lane & 15;
    const int quad = lane >> 4;
    // read-side swizzled chunk offset: phys = quad ^ ((row>>1)&3); rows are
    // 16-multiples + m so f depends only on m.
    const int sw8  = (quad ^ ((m >> 1) & 3)) * 8;

    // staging: 16 A row-groups + 16 B row-groups of 16 rows; wave w owns
    // groups {2w, 2w+1} of each. glds writes linearly: lane l -> row
    // lr=l>>2, phys chunk l&3; fetch global chunk (l&3)^((l>>3)&3) so phys
    // chunk p of row r holds logical p^((r>>1)&3).
    const int lr = lane >> 2;
    const int lc = (lane & 3) ^ ((lane >> 3) & 3);
    const f16_t* gA[2];
    const f16_t* gB[2];
    int offAB[2];
    #pragma unroll
    for (int i = 0; i < 2; i++) {
        int rg = wave * 2 + i;          // 0..15
        gA[i] = Ap + (size_t)(arow0 + rg * 16 + lr) * BK + lc * 8;
        gB[i] = Bp + (size_t)(brow0 + rg * 16 + lr) * BK + lc * 8;
        offAB[i] = rg * 16 * BK;        // wave-uniform LDS base
    }

    floatx4 acc[8][4];
    #pragma unroll
    for (int i = 0; i < 8; i++)
        #pragma unroll
        for (int j = 0; j < 4; j++) acc[i][j] = (floatx4){0.f, 0.f, 0.f, 0.f};

    // prologue: tiles 0 -> slot 0, 1 -> slot 1 (8 glds); vmcnt(4) -> tile 0
    // landed (newest 4 = tile 1); publish.
    STAGE4(0, 0);
    STAGE4(1, 1);
    asm volatile("s_waitcnt vmcnt(4)" ::: "memory");
    __builtin_amdgcn_s_barrier();

    for (int t = 0; t < NKT; ++t) {
        const int rsl = t % 3;
        const int ssl = (t + 2) % 3;
        const int st  = (t + 2 < NKT) ? t + 2 : NKT - 1;  // clamped dummy tail
        // stage tile t+2 into slot (t-1)%3 (readers retired pre-barrier t-1)
        STAGE4(st, ssl);
        // read 12 fragments of tile t (landed: vmcnt(4)+barrier at end of t-1)
        f16x8 ah[8], bh[4];
        #pragma unroll
        for (int s = 0; s < 8; s++)
            ah[s] = *(const f16x8*)&ldsA[rsl][(wm * 128 + s * 16 + m) * BK + sw8];
        #pragma unroll
        for (int s = 0; s < 4; s++)
            bh[s] = *(const f16x8*)&ldsB[rsl][(wn * 64 + s * 16 + m) * BK + sw8];
        __builtin_amdgcn_s_setprio(1);
        #pragma unroll
        for (int i = 0; i < 8; i++)
            #pragma unroll
            for (int j = 0; j < 4; j++)
                acc[i][j] = __builtin_amdgcn_mfma_f32_16x16x32_f16(ah[i], bh[j], acc[i][j], 0, 0, 0);
        __builtin_amdgcn_s_setprio(0);
        // counted gate: newest 4 VMEM = this step's stages (tile t+2) may
        // fly; tile t+1 (staged at t-1) landed. NEVER vmcnt(0) in the loop.
        asm volatile("s_waitcnt vmcnt(4)" ::: "memory");
        __builtin_amdgcn_s_barrier();
    }

    // epilogue: C/D layout col=lane&15 (B-row), row=quad*4+reg (A-row).
    // Norms loaded HERE (frag regs dead) to protect loop register budget.
    const float inv_s2 = 1.0f / 2025.0f;
    float nbv[4];
    #pragma unroll
    for (int j = 0; j < 4; j++) nbv[j] = nB[brow0 + wn * 64 + j * 16 + m];
    float lsum = 0.f;
    #pragma unroll
    for (int i = 0; i < 8; i++) {
        float4 na4 = *(const float4*)&nA[arow0 + wm * 128 + i * 16 + quad * 4];
        #pragma unroll
        for (int j = 0; j < 4; j++)
            #pragma unroll
            for (int r = 0; r < 4; r++) {
                float arg = (2.f * acc[i][j][r] - (&na4.x)[r] - nbv[j]) * inv_s2;
                lsum += __expf(arg);
            }
    }

    // in-wave fp64 reduce (no barriers), then 8-wave LDS combine; plain store
    double d = (double)lsum;
    #pragma unroll
    for (int off = 32; off > 0; off >>= 1) d += __shfl_down(d, off);
    if (lane == 0) wred[wave] = d;
    __syncthreads();
    if (tid == 0) {
        double s = 0.0;
        #pragma unroll
        for (int w = 0; w < 8; w++) s += wred[w];
        partials[b] = s * coef;
    }
}

__global__ __launch_bounds__(256) void final_reduce(const double* __restrict__ partials,
                                                    float* __restrict__ out) {
    __shared__ double red[256];
    int t = threadIdx.x;
    double s = 0.0;
    for (int i = t; i < NBLK; i += 256) s += partials[i];
    red[t] = s;
    __syncthreads();
    for (int off = 128; off > 0; off >>= 1) {
        if (t < off) red[t] += red[t + off];
        __syncthreads();
    }
    if (t == 0) {
        // analytic diagonal subtraction: 1/(n-1) + 1/(m-1)
        double mmd = red[0] - 1.0 / (double)(NROWS - 1) - 1.0 / (double)(MROWS - 1);
        out[0] = (float)mmd;
    }
}

extern "C" void kernel_launch(void* const* d_in, const int* in_sizes, int n_in,
                              void* d_out, int out_size, void* d_ws, size_t ws_size,
                              hipStream_t stream) {
    const float* X = (const float*)d_in[0];   // inputs  [4096,1024] fp32
    const float* Y = (const float*)d_in[1];   // samples [4096,1024] fp32
    float* out = (float*)d_out;

    // workspace: partials | nx | ny | Xp | Yp  (~16.7 MB)
    char* p = (char*)d_ws;
    double* partials = (double*)p;            p += ((size_t)NBLK * sizeof(double) + 255) & ~255ULL;
    float* nx = (float*)p;                    p += (size_t)NROWS * sizeof(float);
    float* ny = (float*)p;                    p += (size_t)MROWS * sizeof(float);
    f16_t* Xp = (f16_t*)p;                    p += (size_t)NROWS * DDIM * sizeof(f16_t);
    f16_t* Yp = (f16_t*)p;

    convert_kernel<<<(NROWS + MROWS) / 4, 256, 0, stream>>>(X, Y, Xp, Yp, nx, ny);
    mmd_mfma<<<NBLK, 512, 0, stream>>>(Xp, Yp, nx, ny, partials);
    final_reduce<<<1, 256, 0, stream>>>(partials, out);
}

// Round 15
// 153.415 us; speedup vs baseline: 1.2558x; 1.2558x over previous
//
#include <hip/hip_runtime.h>
#include <math.h>

// MMD loss, fp16 MFMA. N=M=4096, D=1024, sigma^2=2025.
// Round 25: RESTORE BEST-MEASURED (R13/R17 kernel; 155.6us total, mmd
// 83.0us = 847 TF, MfmaUtil 35%, bank conflicts 0, VGPR 80). R14's
// MFMA-bound-geometry falsifier fired (125us): even with per-wave 128x64,
// a 1-block/CU counted-vmcnt schedule exposes more latency than it hides
// vs the co-resident-block TLP of this structure. Structural matrix fully
// closed: deep pipelines (R1/R2/R3/R14), occupancy push (R4), B-to-regs
// (R5/R10), fat 4-wave tiles (R8), BK=64 (R9), reduce fusion (R6/R12),
// convert rewrite + XCD swizzle (R6/R11) -- all regressed or tied. Durable
// wins kept: (a) packed K-major panels Xp/Yp[kt][row][32] (every glds
// reads 1KB contiguous); (b) true-0-conflict LDS chunk swizzle
// f(r)=((r>>1)&3) on both sides. 128^2/4-wave/TLP drain-loop, triangular
// 2080-block grid, fp64 partials, 3 launches.

typedef _Float16 f16_t;
typedef _Float16 f16x4 __attribute__((ext_vector_type(4)));
typedef _Float16 f16x8 __attribute__((ext_vector_type(8)));
typedef float floatx4 __attribute__((ext_vector_type(4)));

#define NROWS 4096
#define MROWS 4096
#define DDIM  1024
#define BM    128
#define BK    32                      // fp16 elements per K-step (64 B/row)
#define TILE  (BM * BK)               // 4096 f16 per tile (8 KB)
#define NKT   (DDIM / BK)             // 32 K-steps
#define PSTRIDE (4096 * BK)           // f16 elems per packed K-panel (256 KB)
#define NT    (NROWS / BM)            // 32 tiles per dim
#define TRI   (NT * (NT + 1) / 2)     // 528 triangular tiles
#define NBLK  (2 * TRI + NT * NT)     // 2080 blocks

// ---------------------------------------------------------------- convert
// Wave-per-row: 2048 blocks x 4 waves cover 8192 rows. Each lane loads
// 4 float4 (fully coalesced), converts to fp16, stores to the PACKED layout
// Xp[kt][row][32]: lane l, iter c covers k = c*256+l*4 -> panel c*8+(l>>3),
// pos (l&7)*4. Norm of the ROUNDED row shuffle-reduced in-wave.
__global__ __launch_bounds__(256) void convert_kernel(
    const float* __restrict__ X, const float* __restrict__ Y,
    f16_t* __restrict__ Xp, f16_t* __restrict__ Yp,
    float* __restrict__ nx, float* __restrict__ ny) {
    const int wid  = threadIdx.x >> 6;
    const int lane = threadIdx.x & 63;
    const int row  = blockIdx.x * 4 + wid;        // 0..8191
    const float* src;
    f16_t* dstp;
    float* nrm;
    int r;
    if (row < NROWS) {
        r = row;         src = X + (size_t)r * DDIM;
        dstp = Xp;  nrm = nx;
    } else {
        r = row - NROWS; src = Y + (size_t)r * DDIM;
        dstp = Yp;  nrm = ny;
    }
    const float4* s4 = (const float4*)src;        // 256 float4 per row
    float s = 0.f;
    #pragma unroll
    for (int c = 0; c < 4; c++) {
        float4 v = s4[c * 64 + lane];
        f16x4 h;
        h[0] = (f16_t)v.x; h[1] = (f16_t)v.y;
        h[2] = (f16_t)v.z; h[3] = (f16_t)v.w;
        // k = c*256 + lane*4 -> kt = c*8 + (lane>>3), pos = (lane&7)*4
        *(f16x4*)(dstp + (size_t)(c * 8 + (lane >> 3)) * PSTRIDE
                       + (size_t)r * BK + (lane & 7) * 4) = h;
        float h0 = (float)h[0], h1 = (float)h[1];
        float h2 = (float)h[2], h3 = (float)h[3];
        s += h0 * h0 + h1 * h1 + h2 * h2 + h3 * h3;
    }
    #pragma unroll
    for (int off = 32; off > 0; off >>= 1) s += __shfl_down(s, off);
    if (lane == 0) nrm[r] = s;
}

// ---------------------------------------------------------------- main GEMM
__global__ __launch_bounds__(256) void mmd_mfma(
    const f16_t* __restrict__ Xp, const f16_t* __restrict__ Yp,
    const float* __restrict__ nx, const float* __restrict__ ny,
    double* __restrict__ partials) {
    // Split A/B tiles, each BM x BK fp16 = 8 KB. Row r of a tile stores
    // logical chunk c (16 B) at phys chunk c ^ ((r>>1)&3) -- measured 0
    // bank conflicts (R7/R11/R13).
    __shared__ __align__(16) f16_t ldsA[TILE];
    __shared__ __align__(16) f16_t ldsB[TILE];
    __shared__ double wred[4];

    const int b = blockIdx.x;
    const f16_t *Ap, *Bp;             // packed panel bases (panel 0)
    const float *nA, *nB;
    int tr, tc;
    double coef;
    if (b < 2 * TRI) {
        int u = (b < TRI) ? b : b - TRI;
        int r = 0;
        while (u >= NT - r) { u -= NT - r; r++; }
        tr = r; tc = r + u;
        double w = (tr == tc) ? 1.0 : 2.0;   // off-diagonal tiles count twice
        if (b < TRI) { Ap = Xp; Bp = Xp; nA = nx; nB = nx;
                       coef = w / ((double)NROWS * (double)(NROWS - 1)); }
        else         { Ap = Yp; Bp = Yp; nA = ny; nB = ny;
                       coef = w / ((double)MROWS * (double)(MROWS - 1)); }
    } else {
        int u = b - 2 * TRI;
        tr = u >> 5; tc = u & 31;
        Ap = Xp; Bp = Yp; nA = nx; nB = ny;
        coef = -2.0 / ((double)NROWS * (double)MROWS);
    }

    const int t    = threadIdx.x;
    const int wave = t >> 6;            // 0..3; waves 2x2: wm=wave>>1, wn=wave&1
    const int lane = t & 63;
    const int wm   = wave >> 1;
    const int wn   = wave & 1;

    // staging: 16 glds instrs (2 tiles x 8 row-groups of 16 rows); wave w
    // issues instrs w*4 .. w*4+3. Per instr: 16 rows x 64B = CONTIGUOUS 1KB
    // in the packed panel. glds writes linearly: lane l -> row lr=l>>2,
    // phys chunk l&3; lane fetches global chunk (l&3)^((l>>3)&3) so phys
    // chunk p of row r holds logical p^((r>>1)&3).
    const int lr = lane >> 2;           // 0..15 within row-group
    const int lc = (lane & 3) ^ ((lane >> 3) & 3);
    const f16_t* gsrc[4];
    f16_t* ldst[4];
    #pragma unroll
    for (int i = 0; i < 4; i++) {
        int idx = wave * 4 + i;         // 0..15
        int tile = idx >> 3;            // 0=A, 1=B
        int rg   = idx & 7;             // row-group
        const f16_t* base = tile ? (Bp + (size_t)tc * BM * BK)
                                 : (Ap + (size_t)tr * BM * BK);
        gsrc[i] = base + (size_t)(rg * 16 + lr) * BK + lc * 8;
        ldst[i] = (tile ? ldsB : ldsA) + rg * 16 * BK;   // wave-uniform base
    }

    const int m    = lane & 15;         // row within 16x16 subtile
    const int quad = lane >> 4;         // k-chunk: k = quad*8 + j
    // read-side swizzled chunk offset: phys = quad ^ ((row>>1)&3); rows are
    // s*16 + m so f depends only on m.
    const int sw8  = (quad ^ ((m >> 1) & 3)) * 8;

    // hoist epilogue norm loads off the critical tail
    float na[16], nb[4];
    #pragma unroll
    for (int i = 0; i < 4; i++) {
        #pragma unroll
        for (int r = 0; r < 4; r++)
            na[i * 4 + r] = nA[tr * BM + wm * 64 + i * 16 + quad * 4 + r];
        nb[i] = nB[tc * BM + wn * 64 + i * 16 + m];
    }

    floatx4 acc_r[4][4];
    #pragma unroll
    for (int i = 0; i < 4; i++)
        #pragma unroll
        for (int j = 0; j < 4; j++) acc_r[i][j] = (floatx4){0.f, 0.f, 0.f, 0.f};

    for (int kt = 0; kt < NKT; kt++) {
        const size_t ko = (size_t)kt * PSTRIDE;   // next packed K-panel
        __syncthreads();                 // previous compute done before overwrite
        #pragma unroll
        for (int i = 0; i < 4; i++) {
            __builtin_amdgcn_global_load_lds(
                (const __attribute__((address_space(1))) void*)(gsrc[i] + ko),
                (__attribute__((address_space(3))) void*)ldst[i],
                16, 0, 0);
        }
        __syncthreads();                 // drains vmcnt before barrier

        f16x8 ah[4], bh[4];
        #pragma unroll
        for (int s = 0; s < 4; s++) {
            ah[s] = *(const f16x8*)&ldsA[(wm * 64 + s * 16 + m) * BK + sw8];
            bh[s] = *(const f16x8*)&ldsB[(wn * 64 + s * 16 + m) * BK + sw8];
        }
        #pragma unroll
        for (int i = 0; i < 4; i++)
            #pragma unroll
            for (int j = 0; j < 4; j++)
                acc_r[i][j] = __builtin_amdgcn_mfma_f32_16x16x32_f16(ah[i], bh[j], acc_r[i][j], 0, 0, 0);
    }

    // epilogue: C/D layout col=lane&15 (B-row), row=quad*4+reg (A-row)
    const float inv_s2 = 1.0f / 2025.0f;
    float lsum = 0.f;
    #pragma unroll
    for (int i = 0; i < 4; i++)
        #pragma unroll
        for (int j = 0; j < 4; j++)
            #pragma unroll
            for (int r = 0; r < 4; r++) {
                float arg = (2.f * acc_r[i][j][r] - na[i * 4 + r] - nb[j]) * inv_s2;
                lsum += __expf(arg);
            }

    // in-wave fp64 reduce (no barriers), then 4-wave LDS combine; plain store
    double d = (double)lsum;
    #pragma unroll
    for (int off = 32; off > 0; off >>= 1) d += __shfl_down(d, off);
    if (lane == 0) wred[wave] = d;
    __syncthreads();
    if (t == 0)
        partials[b] = (wred[0] + wred[1] + wred[2] + wred[3]) * coef;
}

__global__ __launch_bounds__(256) void final_reduce(const double* __restrict__ partials,
                                                    float* __restrict__ out) {
    __shared__ double red[256];
    int t = threadIdx.x;
    double s = 0.0;
    for (int i = t; i < NBLK; i += 256) s += partials[i];
    red[t] = s;
    __syncthreads();
    for (int off = 128; off > 0; off >>= 1) {
        if (t < off) red[t] += red[t + off];
        __syncthreads();
    }
    if (t == 0) {
        // analytic diagonal subtraction: 1/(n-1) + 1/(m-1)
        double mmd = red[0] - 1.0 / (double)(NROWS - 1) - 1.0 / (double)(MROWS - 1);
        out[0] = (float)mmd;
    }
}

extern "C" void kernel_launch(void* const* d_in, const int* in_sizes, int n_in,
                              void* d_out, int out_size, void* d_ws, size_t ws_size,
                              hipStream_t stream) {
    const float* X = (const float*)d_in[0];   // inputs  [4096,1024] fp32
    const float* Y = (const float*)d_in[1];   // samples [4096,1024] fp32
    float* out = (float*)d_out;

    // workspace: partials | nx | ny | Xp | Yp  (~16.7 MB)
    char* p = (char*)d_ws;
    double* partials = (double*)p;            p += ((size_t)NBLK * sizeof(double) + 255) & ~255ULL;
    float* nx = (float*)p;                    p += (size_t)NROWS * sizeof(float);
    float* ny = (float*)p;                    p += (size_t)MROWS * sizeof(float);
    f16_t* Xp = (f16_t*)p;                    p += (size_t)NROWS * DDIM * sizeof(f16_t);
    f16_t* Yp = (f16_t*)p;

    convert_kernel<<<(NROWS + MROWS) / 4, 256, 0, stream>>>(X, Y, Xp, Yp, nx, ny);
    mmd_mfma<<<NBLK, 256, 0, stream>>>(Xp, Yp, nx, ny, partials);
    final_reduce<<<1, 256, 0, stream>>>(partials, out);
}